// Round 7
// baseline (1473.302 us; speedup 1.0000x reference)
//
#include <hip/hip_runtime.h>
#include <math.h>

// Problem constants (fixed by the reference)
#define BN 256     // batch N
#define TT 1000    // timesteps
#define NO 10      // obs dim
#define NS 10      // state dim
#define HID 64     // GRU hidden
#define DIN 20     // NO + NS
#define G3 192     // 3*HID
#define UR 4       // step-loop unroll / input prefetch depth (1000 % 4 == 0)

typedef float v2f __attribute__((ext_vector_type(2)));

// broadcast lane `l`'s value of v to all lanes (l wave-uniform)
__device__ __forceinline__ float bcast(float v, int l) {
    return __int_as_float(__builtin_amdgcn_readlane(__float_as_int(v), l));
}
__device__ __forceinline__ float rcpf(float x) { return __builtin_amdgcn_rcpf(x); }

// ---------------- Phase 1: GRU recurrence ----------------------------------
// ONE WAVE PER SAMPLE, no barriers, no LDS. Lane j owns hidden unit j and
// holds all weight columns in registers (~360 VGPRs; waves_per_eu(1,1) gives
// the 512-VGPR budget -- R1's 200-VGPR default spilled this).
// Rationale (R5/R6 evidence): every multi-wave k-split pays a ~700+ cyc/step
// cross-SIMD rendezvous (barrier + LDS round trip + skew) that dwarfs its
// issue savings; 8->4 waves cut 580 cyc/step. Zero waves exchanging = zero.
// FP32 throughput comes from v_pk_fma_f32: (r,z) and (n_h, mv) gate pairs
// packed as float2; splat(h_k) x float2-weights.
__global__
__attribute__((amdgpu_flat_work_group_size(64, 64), amdgpu_waves_per_eu(1, 1)))
void gru_phase1(const float* __restrict__ Yi, const float* __restrict__ Xh,
                const float* __restrict__ Wi, const float* __restrict__ Wh,
                const float* __restrict__ bi, const float* __restrict__ bh,
                const float* __restrict__ Wmu, const float* __restrict__ Wvar,
                float* __restrict__ mv_out) {
    const int lane = threadIdx.x;   // hidden unit index
    const int n = blockIdx.x;

    const float* ybase = Yi + (size_t)n * TT * NO;
    const float* xbase = Xh + (size_t)n * TT * NS;
    float* obase = mv_out + (size_t)n * TT * DIN;

    // ---- per-lane weight columns, gate-pair packed ----
    v2f wrz[HID];    // {Wh_r, Wh_z} column elements
    v2f wnm[HID];    // {Wh_n, packed W_mu/W_var} column elements
    v2f wirz[DIN];   // {Wi_r, Wi_z}
    float win_[DIN]; // Wi_n
#pragma unroll
    for (int k = 0; k < HID; ++k) {
        wrz[k].x = Wh[k * G3 + lane];
        wrz[k].y = Wh[k * G3 + 64 + lane];
        float wm = (lane < NS) ? Wmu[k * NS + lane]
                 : (lane < 2 * NS) ? Wvar[k * NS + (lane - NS)] : 0.0f;
        wnm[k].x = Wh[k * G3 + 128 + lane];
        wnm[k].y = wm;  // lanes 0..9 -> W_mu col, 10..19 -> W_var col
    }
#pragma unroll
    for (int d = 0; d < DIN; ++d) {
        wirz[d].x = Wi[d * G3 + lane];
        wirz[d].y = Wi[d * G3 + 64 + lane];
        win_[d]   = Wi[d * G3 + 128 + lane];
    }
    v2f brz;
    brz.x = bi[lane] + bh[lane];
    brz.y = bi[64 + lane] + bh[64 + lane];
    const float bxn = bi[128 + lane];
    const float bhn = bh[128 + lane];

    // input loader: lane d<20 holds x_t[d] = concat(y_t, xhat_t)[d]
    auto loadx = [&](int t) -> float {
        float v = 0.0f;
        if (lane < NO) v = ybase[(size_t)t * NO + lane];
        else if (lane < DIN) v = xbase[(size_t)t * NS + (lane - NO)];
        return v;
    };

    float h = 0.0f;
    // register input prefetch, UR steps deep (no barrier -> never drained)
    float xq0 = loadx(0), xq1 = loadx(1), xq2 = loadx(2), xq3 = loadx(3);

    // one GRU step; x = this step's input (lanes 0..19), t = step index.
    // Also emits output row t-1 (projection of h_{t-1} rides the broadcast).
    auto step = [&](float x, int t) {
        // input projection (r,z packed; n scalar), 2-way acc split
        v2f arz0 = brz, arz1 = {0.0f, 0.0f};
        float ax0 = bxn, ax1 = 0.0f;
#pragma unroll
        for (int d = 0; d < DIN; d += 2) {
            float s0 = bcast(x, d);
            float s1 = bcast(x, d + 1);
            arz0 += s0 * wirz[d];
            arz1 += s1 * wirz[d + 1];
            ax0 = fmaf(s0, win_[d], ax0);
            ax1 = fmaf(s1, win_[d + 1], ax1);
        }
        // hidden projection, 4-way acc split (issue-bound, not latency-bound)
        v2f hrz0 = {0,0}, hrz1 = {0,0}, hrz2 = {0,0}, hrz3 = {0,0};
        v2f hnm0 = {0,0}, hnm1 = {0,0}, hnm2 = {0,0}, hnm3 = {0,0};
#pragma unroll
        for (int k = 0; k < HID; k += 4) {
            float s0 = bcast(h, k);
            float s1 = bcast(h, k + 1);
            float s2 = bcast(h, k + 2);
            float s3 = bcast(h, k + 3);
            hrz0 += s0 * wrz[k];     hnm0 += s0 * wnm[k];
            hrz1 += s1 * wrz[k + 1]; hnm1 += s1 * wnm[k + 1];
            hrz2 += s2 * wrz[k + 2]; hnm2 += s2 * wnm[k + 2];
            hrz3 += s3 * wrz[k + 3]; hnm3 += s3 * wnm[k + 3];
        }
        const v2f arz = (arz0 + arz1) + ((hrz0 + hrz1) + (hrz2 + hrz3));
        const v2f anm = (hnm0 + hnm1) + (hnm2 + hnm3);
        const float ar = arz.x, az = arz.y;
        const float anx = ax0 + ax1;
        const float anh = bhn + anm.x;
        // output row t-1: projection of h_{t-1} (skip t==0)
        if (t > 0 && lane < DIN)
            obase[(size_t)(t - 1) * DIN + lane] = anm.y;

        float r = rcpf(1.0f + __expf(-ar));
        float z = rcpf(1.0f + __expf(-az));
        float pre = fmaf(r, anh, anx);
        float e2 = __expf(2.0f * pre);          // inf-safe: nn -> +/-1
        float nn = 1.0f - 2.0f * rcpf(e2 + 1.0f);
        h = fmaf(z, h - nn, nn);                // (1-z)*n + z*h
    };

#pragma unroll 1
    for (int tb = 0; tb < TT; tb += UR) {
        // issue next prefetches first (stay in flight ~UR steps)
        float p0 = (tb + UR + 0 < TT) ? loadx(tb + UR + 0) : 0.0f;
        float p1 = (tb + UR + 1 < TT) ? loadx(tb + UR + 1) : 0.0f;
        float p2 = (tb + UR + 2 < TT) ? loadx(tb + UR + 2) : 0.0f;
        float p3 = (tb + UR + 3 < TT) ? loadx(tb + UR + 3) : 0.0f;
        step(xq0, tb + 0);
        step(xq1, tb + 1);
        step(xq2, tb + 2);
        step(xq3, tb + 3);
        xq0 = p0; xq1 = p1; xq2 = p2; xq3 = p3;
    }

    // epilogue: output row 999 from h_999
    {
        float amv = 0.0f;
#pragma unroll
        for (int k = 0; k < HID; ++k)
            amv = fmaf(bcast(h, k), wnm[k].y, amv);
        if (lane < DIN)
            obase[(size_t)(TT - 1) * DIN + lane] = amv;
    }
}

// ---------------- d_out init: the constant term ----------------------------
__global__ void init_out(float* out) {
    // -0.5*NO*T*log(2pi) / (T*NO) = -0.5*log(2pi)
    out[0] = -0.918938533204672742f;
}

// ---------------- Phase 2: per-(n,t) Gaussian log-lik ----------------------
__global__ __launch_bounds__(256)
void lik_phase2(const float* __restrict__ Yi, const float* __restrict__ Cw,
                const float* __restrict__ Hm, const float* __restrict__ mu_w,
                const float* __restrict__ b_mu, const float* __restrict__ b_var,
                const float* __restrict__ mv_in, float* __restrict__ out) {
    __shared__ float sH[NO * NS];
    __shared__ float smw[NO], sbm[NS], sbv[NS];
    __shared__ float ssum[4];
    const int tid = threadIdx.x;
    if (tid < NO * NS) sH[tid] = Hm[tid];
    if (tid < NO) smw[tid] = mu_w[tid];
    if (tid < NS) { sbm[tid] = b_mu[tid]; sbv[tid] = b_var[tid]; }
    __syncthreads();

    const int gid = blockIdx.x * 256 + tid;   // 0 .. BN*TT-1
    float contrib = 0.0f;
    if (gid < BN * TT) {
        const int n = gid / TT;
        const float* mv = mv_in + (size_t)gid * DIN;
        float mu[NS], va[NS];
#pragma unroll
        for (int i = 0; i < NS; ++i) {
            mu[i] = mv[i] + sbm[i];
            float x = mv[NS + i] + sbv[i];
            va[i] = (x > 0.0f) ? (x + log1pf(__expf(-x))) : log1pf(__expf(x));
        }
        const float* y = Yi + (size_t)gid * NO;
        float e[NO];
#pragma unroll
        for (int i = 0; i < NO; ++i) {
            float m = smw[i];
#pragma unroll
            for (int j = 0; j < NS; ++j) m = fmaf(sH[i * NS + j], mu[j], m);
            e[i] = y[i] - m;
        }
        // M = H diag(va) H^T + Cw (lower triangle only)
        float M[NO][NO];
        const float* cw = Cw + (size_t)n * NO * NO;
#pragma unroll
        for (int i = 0; i < NO; ++i)
#pragma unroll
            for (int j = 0; j <= i; ++j) M[i][j] = cw[i * NO + j];
#pragma unroll
        for (int l = 0; l < NS; ++l) {
            float vl = va[l];
            float hv[NO];
#pragma unroll
            for (int i = 0; i < NO; ++i) hv[i] = sH[i * NS + l];
#pragma unroll
            for (int i = 0; i < NO; ++i) {
                float hvi = hv[i] * vl;
#pragma unroll
                for (int j = 0; j <= i; ++j) M[i][j] = fmaf(hvi, hv[j], M[i][j]);
            }
        }
        // in-place Cholesky (lower). logdet via single log of prod(d_j)
        // (d_j in ~[0.3, 50] -> product safely within fp32 range).
        // 1/L_jj = 1/sqrt(d_j) = rs exactly -> forward solve uses rs directly.
        float dprod = 1.0f;
        float drs[NO];                  // 1/sqrt(d_j)
#pragma unroll
        for (int j = 0; j < NO; ++j) {
            float d = M[j][j];
#pragma unroll
            for (int k = 0; k < j; ++k) d = fmaf(-M[j][k], M[j][k], d);
            dprod *= d;
            float rs = __frsqrt_rn(d);
            drs[j] = rs;
#pragma unroll
            for (int i = j + 1; i < NO; ++i) {
                float v = M[i][j];
#pragma unroll
                for (int k = 0; k < j; ++k) v = fmaf(-M[i][k], M[j][k], v);
                M[i][j] = v * rs;
            }
        }
        const float logdet = __logf(dprod);
        // quad = || L^-1 e ||^2 (forward solve; L_ii = 1/drs[i])
        float wv[NO];
        float quad = 0.0f;
#pragma unroll
        for (int i = 0; i < NO; ++i) {
            float v = e[i];
#pragma unroll
            for (int k = 0; k < i; ++k) v = fmaf(-M[i][k], wv[k], v);
            wv[i] = v * drs[i];
            quad = fmaf(wv[i], wv[i], quad);
        }
        const float SCALE = 0.5f / ((float)BN * (float)TT * (float)NO);
        contrib = -(logdet + quad) * SCALE;
    }

    // block reduction: wave shuffle, LDS across 4 waves, one atomic
#pragma unroll
    for (int off = 32; off > 0; off >>= 1) contrib += __shfl_down(contrib, off);
    if ((tid & 63) == 0) ssum[tid >> 6] = contrib;
    __syncthreads();
    if (tid == 0) {
        float s = ssum[0] + ssum[1] + ssum[2] + ssum[3];
        atomicAdd(out, s);
    }
}

// ---------------- launch ---------------------------------------------------
extern "C" void kernel_launch(void* const* d_in, const int* in_sizes, int n_in,
                              void* d_out, int out_size, void* d_ws, size_t ws_size,
                              hipStream_t stream) {
    const float* Yi    = (const float*)d_in[0];
    const float* Xh    = (const float*)d_in[1];
    const float* Cw    = (const float*)d_in[2];
    const float* Hm    = (const float*)d_in[3];
    const float* mu_w  = (const float*)d_in[4];
    const float* Wi    = (const float*)d_in[5];
    const float* Wh    = (const float*)d_in[6];
    const float* bi    = (const float*)d_in[7];
    const float* bh    = (const float*)d_in[8];
    const float* W_mu  = (const float*)d_in[9];
    const float* b_mu  = (const float*)d_in[10];
    const float* W_var = (const float*)d_in[11];
    const float* b_var = (const float*)d_in[12];
    float* out = (float*)d_out;
    float* mv  = (float*)d_ws;   // [BN*TT*DIN] floats = 20.48 MB

    init_out<<<1, 1, 0, stream>>>(out);
    gru_phase1<<<dim3(BN), dim3(64), 0, stream>>>(Yi, Xh, Wi, Wh, bi, bh,
                                                  W_mu, W_var, mv);
    lik_phase2<<<dim3((BN * TT + 255) / 256), dim3(256), 0, stream>>>(
        Yi, Cw, Hm, mu_w, b_mu, b_var, mv, out);
}

// Round 8
// 1146.941 us; speedup vs baseline: 1.2845x; 1.2845x over previous
//
#include <hip/hip_runtime.h>
#include <hip/hip_fp16.h>
#include <math.h>

// Problem constants (fixed by the reference)
#define BN 256     // batch N
#define TT 1000    // timesteps
#define NO 10      // obs dim
#define NS 10      // state dim
#define HID 64     // GRU hidden
#define DIN 20     // NO + NS
#define G3 192     // 3*HID
#define WV 4       // waves per sample (k-split)
#define KW 16      // HID / WV
#define GS 8       // steps per group (1000 = 125 * 8)
#define NG 125     // groups
#define C_HALF_LOG2PI -0.918938533204672742f

// broadcast lane `l`'s value of v to all lanes (l wave-uniform)
__device__ __forceinline__ float bcast(float v, int l) {
    return __int_as_float(__builtin_amdgcn_readlane(__float_as_int(v), l));
}
__device__ __forceinline__ float rcpf(float x) { return __builtin_amdgcn_rcpf(x); }

// Workgroup barrier WITHOUT the vmcnt(0) drain __syncthreads() emits.
// LDS ordering needs only lgkmcnt(0); global loads/stores issued before the
// barrier stay in flight.
__device__ __forceinline__ void sync_lds() {
    asm volatile("s_waitcnt lgkmcnt(0)\n\ts_barrier" ::: "memory");
}

// ============================================================================
// PRIMARY path (ws >= 32.8 MB): phase 1 stores h_t (fp16); phase 2 computes
// the mu/var projections from h. Phase 1 exchange = exactly one float4.
// ============================================================================

// ---------------- Phase 1: GRU recurrence, store h ------------------------
// One sample per block, 4 waves. Per step: 21 bcast + 63 fma pre-barrier,
// 1 ds_write_b128, barrier, 4 ds_read_b128 + nonlinearity. Nothing else:
// no pamv sidecar, no obuf, no inbuf (inputs ride registers via readlane;
// each wave loads its own 5 dims x 8 steps once per group, lanes 0..39).
// R7 lesson: per-lane arrays of 64 NEVER promote (scratch); 16 is safe.
__global__
__attribute__((amdgpu_flat_work_group_size(256, 256), amdgpu_waves_per_eu(1, 1)))
void gru_h(const float* __restrict__ Yi, const float* __restrict__ Xh,
           const float* __restrict__ Wi, const float* __restrict__ Wh,
           const float* __restrict__ bi, const float* __restrict__ bh,
           __half* __restrict__ hout) {
    const int tid = threadIdx.x;
    const int lane = tid & 63;      // hidden unit index
    const int w = tid >> 6;         // wave id 0..3
    const int kb = w * KW;          // k-range base (hidden)

    // packed partials: [buf][wave][lane] = {r, z, nx, nh}  (8 KB, only LDS)
    __shared__ float4 part[2][WV][HID];

    const int n = blockIdx.x;
    const float* ybase = Yi + (size_t)n * TT * NO;
    const float* xbase = Xh + (size_t)n * TT * NS;
    __half* hbase = hout + (size_t)n * TT * HID;

    // ---- per-lane weight slices (16-element arrays: register-resident) ----
    float whr[KW], whz[KW], whn[KW];
#pragma unroll
    for (int k = 0; k < KW; ++k) {
        const int kk = kb + k;
        whr[k] = Wh[kk * G3 + lane];
        whz[k] = Wh[kk * G3 + 64 + lane];
        whn[k] = Wh[kk * G3 + 128 + lane];
    }
    float wir[5], wiz[5], win[5];
#pragma unroll
    for (int k = 0; k < 5; ++k) {
        const int d = 5 * w + k;    // this wave's input dims
        wir[k] = Wi[d * G3 + lane];
        wiz[k] = Wi[d * G3 + 64 + lane];
        win[k] = Wi[d * G3 + 128 + lane];
    }
    const float b_r  = bi[lane] + bh[lane];
    const float b_z  = bi[64 + lane] + bh[64 + lane];
    const float bx_n = bi[128 + lane];
    const float bh_n = bh[128 + lane];

    // per-wave input block: 5 dims x 8 steps in lanes 0..39 (lane 5s+d)
    const float* src = (w < 2) ? ybase : xbase;
    const int off5 = (w & 1) * 5;
    const int ls = lane / 5;
    const int ld = lane - 5 * ls;
    const bool lact = (lane < 40);

    // group 0 inputs (one-time vmcnt stall at step 0)
    float xcur = lact ? src[10 * ls + off5 + ld] : 0.0f;
    float h = 0.0f;

#pragma unroll 1
    for (int g = 0; g < NG; ++g) {
        // next group's inputs: issued now, first readlane-use is next group
        // (sync_lds never drains vmcnt -> stays in flight ~8 steps)
        float xnext = 0.0f;
        if (lact && (g + 1) < NG)
            xnext = src[(size_t)(g + 1) * 80 + 10 * ls + off5 + ld];

#pragma unroll
        for (int s = 0; s < GS; ++s) {
            const int t = 8 * g + s;
            // ---- pre-barrier: partials (input proj + this wave's 16 k's) ----
            const float x0 = bcast(xcur, 5 * s + 0);
            const float x1 = bcast(xcur, 5 * s + 1);
            const float x2 = bcast(xcur, 5 * s + 2);
            const float x3 = bcast(xcur, 5 * s + 3);
            const float x4 = bcast(xcur, 5 * s + 4);
            float pr = x0 * wir[0], pz = x0 * wiz[0], px = x0 * win[0];
            pr = fmaf(x1, wir[1], pr); pz = fmaf(x1, wiz[1], pz); px = fmaf(x1, win[1], px);
            pr = fmaf(x2, wir[2], pr); pz = fmaf(x2, wiz[2], pz); px = fmaf(x2, win[2], px);
            pr = fmaf(x3, wir[3], pr); pz = fmaf(x3, wiz[3], pz); px = fmaf(x3, win[3], px);
            pr = fmaf(x4, wir[4], pr); pz = fmaf(x4, wiz[4], pz); px = fmaf(x4, win[4], px);
            float pn = 0.0f;
#pragma unroll
            for (int k = 0; k < KW; ++k) {
                float sv = bcast(h, kb + k);
                pr = fmaf(sv, whr[k], pr);
                pz = fmaf(sv, whz[k], pz);
                pn = fmaf(sv, whn[k], pn);
            }
            const int bufp = s & 1;
            part[bufp][w][lane] = make_float4(pr, pz, px, pn);
            sync_lds();

            // ---- post-barrier: reduce + nonlinearity (all waves, identical) --
            const float4 q0 = part[bufp][0][lane];
            const float4 q1 = part[bufp][1][lane];
            const float4 q2 = part[bufp][2][lane];
            const float4 q3 = part[bufp][3][lane];
            const float ar = b_r  + ((q0.x + q1.x) + (q2.x + q3.x));
            const float az = b_z  + ((q0.y + q1.y) + (q2.y + q3.y));
            const float ax = bx_n + ((q0.z + q1.z) + (q2.z + q3.z));
            const float ah = bh_n + ((q0.w + q1.w) + (q2.w + q3.w));
            float r = rcpf(1.0f + __expf(-ar));
            float z = rcpf(1.0f + __expf(-az));
            float pre = fmaf(r, ah, ax);
            float e2 = __expf(2.0f * pre);       // inf-safe: nn -> +/-1
            float nn = 1.0f - 2.0f * rcpf(e2 + 1.0f);
            h = fmaf(z, h - nn, nn);             // (1-z)*n + z*h
            // store h_t (fire-and-forget; |h|<1 so fp16 rel err ~5e-4)
            if (w == 0)
                hbase[(size_t)t * HID + lane] = __float2half(h);
        }
        xcur = xnext;
    }
}

// ---------------- Phase 2 (primary): log-lik from h ------------------------
__global__ __launch_bounds__(256)
void lik_h(const float* __restrict__ Yi, const float* __restrict__ Cw,
           const float* __restrict__ Hm, const float* __restrict__ mu_w,
           const float* __restrict__ Wmu, const float* __restrict__ b_mu,
           const float* __restrict__ Wvar, const float* __restrict__ b_var,
           const __half* __restrict__ hbuf, float* __restrict__ out) {
    __shared__ float sWm[HID][12];   // rows padded to 12 -> 16B-aligned rows
    __shared__ float sWv[HID][12];
    __shared__ float sH[NO * NS];
    __shared__ float smw[NO], sbm[NS], sbv[NS];
    __shared__ float ssum[4];
    const int tid = threadIdx.x;
    for (int i = tid; i < HID * NS; i += 256) {
        sWm[i / NS][i % NS] = Wmu[i];
        sWv[i / NS][i % NS] = Wvar[i];
    }
    if (tid < NO * NS) sH[tid] = Hm[tid];
    if (tid < NO) smw[tid] = mu_w[tid];
    if (tid < NS) { sbm[tid] = b_mu[tid]; sbv[tid] = b_var[tid]; }
    __syncthreads();

    const int gid = blockIdx.x * 256 + tid;   // 0 .. BN*TT-1
    float contrib = 0.0f;
    if (gid < BN * TT) {
        const int n = gid / TT;
        // ---- mu/var projections from h (LDS weight reads broadcast) ----
        float mu[NS], va[NS];
#pragma unroll
        for (int i = 0; i < NS; ++i) { mu[i] = sbm[i]; va[i] = sbv[i]; }
        const uint4* hp = (const uint4*)(hbuf + (size_t)gid * HID);
#pragma unroll
        for (int c = 0; c < 8; ++c) {
            const uint4 u = hp[c];
            float hk[8];
            float2 f;
            f = __half22float2(*(const __half2*)&u.x); hk[0] = f.x; hk[1] = f.y;
            f = __half22float2(*(const __half2*)&u.y); hk[2] = f.x; hk[3] = f.y;
            f = __half22float2(*(const __half2*)&u.z); hk[4] = f.x; hk[5] = f.y;
            f = __half22float2(*(const __half2*)&u.w); hk[6] = f.x; hk[7] = f.y;
#pragma unroll
            for (int j = 0; j < 8; ++j) {
                const int k = 8 * c + j;
                const float x = hk[j];
                const float4 m0 = *(const float4*)&sWm[k][0];
                const float4 m1 = *(const float4*)&sWm[k][4];
                const float2 m2 = *(const float2*)&sWm[k][8];
                const float4 v0 = *(const float4*)&sWv[k][0];
                const float4 v1 = *(const float4*)&sWv[k][4];
                const float2 v2 = *(const float2*)&sWv[k][8];
                mu[0] = fmaf(x, m0.x, mu[0]); mu[1] = fmaf(x, m0.y, mu[1]);
                mu[2] = fmaf(x, m0.z, mu[2]); mu[3] = fmaf(x, m0.w, mu[3]);
                mu[4] = fmaf(x, m1.x, mu[4]); mu[5] = fmaf(x, m1.y, mu[5]);
                mu[6] = fmaf(x, m1.z, mu[6]); mu[7] = fmaf(x, m1.w, mu[7]);
                mu[8] = fmaf(x, m2.x, mu[8]); mu[9] = fmaf(x, m2.y, mu[9]);
                va[0] = fmaf(x, v0.x, va[0]); va[1] = fmaf(x, v0.y, va[1]);
                va[2] = fmaf(x, v0.z, va[2]); va[3] = fmaf(x, v0.w, va[3]);
                va[4] = fmaf(x, v1.x, va[4]); va[5] = fmaf(x, v1.y, va[5]);
                va[6] = fmaf(x, v1.z, va[6]); va[7] = fmaf(x, v1.w, va[7]);
                va[8] = fmaf(x, v2.x, va[8]); va[9] = fmaf(x, v2.y, va[9]);
            }
        }
        // stable softplus on va
#pragma unroll
        for (int i = 0; i < NS; ++i) {
            float x = va[i];
            va[i] = (x > 0.0f) ? (x + log1pf(__expf(-x))) : log1pf(__expf(x));
        }
        const float* y = Yi + (size_t)gid * NO;
        float e[NO];
#pragma unroll
        for (int i = 0; i < NO; ++i) {
            float m = smw[i];
#pragma unroll
            for (int j = 0; j < NS; ++j) m = fmaf(sH[i * NS + j], mu[j], m);
            e[i] = y[i] - m;
        }
        // M = H diag(va) H^T + Cw (lower triangle only)
        float M[NO][NO];
        const float* cw = Cw + (size_t)n * NO * NO;
#pragma unroll
        for (int i = 0; i < NO; ++i)
#pragma unroll
            for (int j = 0; j <= i; ++j) M[i][j] = cw[i * NO + j];
#pragma unroll
        for (int l = 0; l < NS; ++l) {
            float vl = va[l];
            float hv[NO];
#pragma unroll
            for (int i = 0; i < NO; ++i) hv[i] = sH[i * NS + l];
#pragma unroll
            for (int i = 0; i < NO; ++i) {
                float hvi = hv[i] * vl;
#pragma unroll
                for (int j = 0; j <= i; ++j) M[i][j] = fmaf(hvi, hv[j], M[i][j]);
            }
        }
        // Cholesky; logdet = log(prod d_j); forward solve with 1/L_jj = rs
        float dprod = 1.0f;
        float drs[NO];
#pragma unroll
        for (int j = 0; j < NO; ++j) {
            float d = M[j][j];
#pragma unroll
            for (int k = 0; k < j; ++k) d = fmaf(-M[j][k], M[j][k], d);
            dprod *= d;
            float rs = __frsqrt_rn(d);
            drs[j] = rs;
#pragma unroll
            for (int i = j + 1; i < NO; ++i) {
                float v = M[i][j];
#pragma unroll
                for (int k = 0; k < j; ++k) v = fmaf(-M[i][k], M[j][k], v);
                M[i][j] = v * rs;
            }
        }
        const float logdet = __logf(dprod);
        float wv[NO];
        float quad = 0.0f;
#pragma unroll
        for (int i = 0; i < NO; ++i) {
            float v = e[i];
#pragma unroll
            for (int k = 0; k < i; ++k) v = fmaf(-M[i][k], wv[k], v);
            wv[i] = v * drs[i];
            quad = fmaf(wv[i], wv[i], quad);
        }
        const float SCALE = 0.5f / ((float)BN * (float)TT * (float)NO);
        contrib = -(logdet + quad) * SCALE;
    }

#pragma unroll
    for (int off = 32; off > 0; off >>= 1) contrib += __shfl_down(contrib, off);
    if ((tid & 63) == 0) ssum[tid >> 6] = contrib;
    __syncthreads();
    if (tid == 0) {
        float s = ssum[0] + ssum[1] + ssum[2] + ssum[3];
        if (blockIdx.x == 0) s += C_HALF_LOG2PI;   // d_out memset to 0 pre-launch
        atomicAdd(out, s);
    }
}

// ============================================================================
// FALLBACK path (ws too small): R6 kernels (mv projections in phase 1)
// ============================================================================
__global__
__attribute__((amdgpu_flat_work_group_size(256, 256), amdgpu_waves_per_eu(1, 1)))
void gru_fb(const float* __restrict__ Yi, const float* __restrict__ Xh,
            const float* __restrict__ Wi, const float* __restrict__ Wh,
            const float* __restrict__ bi, const float* __restrict__ bh,
            const float* __restrict__ Wmu, const float* __restrict__ Wvar,
            float* __restrict__ mv_out) {
    const int tid = threadIdx.x;
    const int lane = tid & 63;
    const int w = tid >> 6;
    const int kb = w * KW;
    __shared__ float4 part[2][WV][HID];
    __shared__ float pamv[2][WV][HID];
    __shared__ float inbuf[2][GS * DIN];
    __shared__ float obuf[2][GS * DIN];
    const int n = blockIdx.x;
    const float* ybase = Yi + (size_t)n * TT * NO;
    const float* xbase = Xh + (size_t)n * TT * NS;
    float* obase = mv_out + (size_t)n * TT * DIN;
    float whr[KW], whz[KW], whn[KW], wmv[KW];
    float wir[5], wiz[5], win[5];
#pragma unroll
    for (int k = 0; k < KW; ++k) {
        const int kk = kb + k;
        whr[k] = Wh[kk * G3 + lane];
        whz[k] = Wh[kk * G3 + 64 + lane];
        whn[k] = Wh[kk * G3 + 128 + lane];
        float wm = (lane < NS) ? Wmu[kk * NS + lane] : 0.0f;
        float wvv = (lane >= NS && lane < 2 * NS) ? Wvar[kk * NS + (lane - NS)] : 0.0f;
        wmv[k] = wm + wvv;
    }
#pragma unroll
    for (int k = 0; k < 5; ++k) {
        const int d = 5 * w + k;
        wir[k] = Wi[d * G3 + lane];
        wiz[k] = Wi[d * G3 + 64 + lane];
        win[k] = Wi[d * G3 + 128 + lane];
    }
    const float b_r  = bi[lane] + bh[lane];
    const float b_z  = bi[64 + lane] + bh[64 + lane];
    const float bx_n = bi[128 + lane];
    const float bh_n = bh[128 + lane];
    const int ibase = ((w >= 2) ? 80 : 0) + (w & 1) * 5;
    if (tid < 160)
        inbuf[0][tid] = (tid < 80) ? ybase[tid] : xbase[tid - 80];
    sync_lds();
    float h = 0.0f;
#pragma unroll 1
    for (int g = 0; g < NG; ++g) {
        float ld = 0.0f;
        const bool do_ld = (tid < 160) && (g + 1 < NG);
        if (do_ld)
            ld = (tid < 80) ? ybase[(size_t)(g + 1) * 80 + tid]
                            : xbase[(size_t)(g + 1) * 80 + (tid - 80)];
        const float* ib = inbuf[g & 1];
#pragma unroll
        for (int s = 0; s < GS; ++s) {
            const int ro = ibase + 10 * s;
            const float x0 = ib[ro], x1 = ib[ro + 1], x2 = ib[ro + 2];
            const float x3 = ib[ro + 3], x4 = ib[ro + 4];
            float pr = x0 * wir[0], pz = x0 * wiz[0], px = x0 * win[0];
            pr = fmaf(x1, wir[1], pr); pz = fmaf(x1, wiz[1], pz); px = fmaf(x1, win[1], px);
            pr = fmaf(x2, wir[2], pr); pz = fmaf(x2, wiz[2], pz); px = fmaf(x2, win[2], px);
            pr = fmaf(x3, wir[3], pr); pz = fmaf(x3, wiz[3], pz); px = fmaf(x3, win[3], px);
            pr = fmaf(x4, wir[4], pr); pz = fmaf(x4, wiz[4], pz); px = fmaf(x4, win[4], px);
            float pn = 0.0f, pm = 0.0f;
#pragma unroll
            for (int k = 0; k < KW; ++k) {
                float sv = bcast(h, kb + k);
                pr = fmaf(sv, whr[k], pr);
                pz = fmaf(sv, whz[k], pz);
                pn = fmaf(sv, whn[k], pn);
                pm = fmaf(sv, wmv[k], pm);
            }
            const int bufp = s & 1;
            part[bufp][w][lane] = make_float4(pr, pz, px, pn);
            pamv[bufp][w][lane] = pm;
            if (s == GS - 1 && do_ld) inbuf[(g + 1) & 1][tid] = ld;
            sync_lds();
            const float4 q0 = part[bufp][0][lane];
            const float4 q1 = part[bufp][1][lane];
            const float4 q2 = part[bufp][2][lane];
            const float4 q3 = part[bufp][3][lane];
            const float ar = b_r  + ((q0.x + q1.x) + (q2.x + q3.x));
            const float az = b_z  + ((q0.y + q1.y) + (q2.y + q3.y));
            const float ax = bx_n + ((q0.z + q1.z) + (q2.z + q3.z));
            const float ah = bh_n + ((q0.w + q1.w) + (q2.w + q3.w));
            if (w == 3) {
                float amv = (pamv[bufp][0][lane] + pamv[bufp][1][lane])
                          + (pamv[bufp][2][lane] + pamv[bufp][3][lane]);
                if (lane < DIN && !(g == 0 && s == 0)) {
                    const int tm1 = 8 * g + s - 1;
                    obuf[(tm1 >> 3) & 1][(tm1 & 7) * DIN + lane] = amv;
                }
            }
            if (s == 1 && g >= 1 && tid < 160)
                obase[(size_t)(g - 1) * 160 + tid] = obuf[(g - 1) & 1][tid];
            float r = rcpf(1.0f + __expf(-ar));
            float z = rcpf(1.0f + __expf(-az));
            float pre = fmaf(r, ah, ax);
            float e2 = __expf(2.0f * pre);
            float nn = 1.0f - 2.0f * rcpf(e2 + 1.0f);
            h = fmaf(z, h - nn, nn);
        }
    }
    {
        float pm = 0.0f;
#pragma unroll
        for (int k = 0; k < KW; ++k) pm = fmaf(bcast(h, kb + k), wmv[k], pm);
        pamv[0][w][lane] = pm;
        sync_lds();
        if (w == 3 && lane < DIN) {
            float amv = (pamv[0][0][lane] + pamv[0][1][lane])
                      + (pamv[0][2][lane] + pamv[0][3][lane]);
            obuf[0][7 * DIN + lane] = amv;
        }
        sync_lds();
        if (tid < 160)
            obase[(size_t)(NG - 1) * 160 + tid] = obuf[0][tid];
    }
}

__global__ __launch_bounds__(256)
void lik_fb(const float* __restrict__ Yi, const float* __restrict__ Cw,
            const float* __restrict__ Hm, const float* __restrict__ mu_w,
            const float* __restrict__ b_mu, const float* __restrict__ b_var,
            const float* __restrict__ mv_in, float* __restrict__ out) {
    __shared__ float sH[NO * NS];
    __shared__ float smw[NO], sbm[NS], sbv[NS];
    __shared__ float ssum[4];
    const int tid = threadIdx.x;
    if (tid < NO * NS) sH[tid] = Hm[tid];
    if (tid < NO) smw[tid] = mu_w[tid];
    if (tid < NS) { sbm[tid] = b_mu[tid]; sbv[tid] = b_var[tid]; }
    __syncthreads();
    const int gid = blockIdx.x * 256 + tid;
    float contrib = 0.0f;
    if (gid < BN * TT) {
        const int n = gid / TT;
        const float* mv = mv_in + (size_t)gid * DIN;
        float mu[NS], va[NS];
#pragma unroll
        for (int i = 0; i < NS; ++i) {
            mu[i] = mv[i] + sbm[i];
            float x = mv[NS + i] + sbv[i];
            va[i] = (x > 0.0f) ? (x + log1pf(__expf(-x))) : log1pf(__expf(x));
        }
        const float* y = Yi + (size_t)gid * NO;
        float e[NO];
#pragma unroll
        for (int i = 0; i < NO; ++i) {
            float m = smw[i];
#pragma unroll
            for (int j = 0; j < NS; ++j) m = fmaf(sH[i * NS + j], mu[j], m);
            e[i] = y[i] - m;
        }
        float M[NO][NO];
        const float* cw = Cw + (size_t)n * NO * NO;
#pragma unroll
        for (int i = 0; i < NO; ++i)
#pragma unroll
            for (int j = 0; j <= i; ++j) M[i][j] = cw[i * NO + j];
#pragma unroll
        for (int l = 0; l < NS; ++l) {
            float vl = va[l];
            float hv[NO];
#pragma unroll
            for (int i = 0; i < NO; ++i) hv[i] = sH[i * NS + l];
#pragma unroll
            for (int i = 0; i < NO; ++i) {
                float hvi = hv[i] * vl;
#pragma unroll
                for (int j = 0; j <= i; ++j) M[i][j] = fmaf(hvi, hv[j], M[i][j]);
            }
        }
        float dprod = 1.0f;
        float drs[NO];
#pragma unroll
        for (int j = 0; j < NO; ++j) {
            float d = M[j][j];
#pragma unroll
            for (int k = 0; k < j; ++k) d = fmaf(-M[j][k], M[j][k], d);
            dprod *= d;
            float rs = __frsqrt_rn(d);
            drs[j] = rs;
#pragma unroll
            for (int i = j + 1; i < NO; ++i) {
                float v = M[i][j];
#pragma unroll
                for (int k = 0; k < j; ++k) v = fmaf(-M[i][k], M[j][k], v);
                M[i][j] = v * rs;
            }
        }
        const float logdet = __logf(dprod);
        float wv[NO];
        float quad = 0.0f;
#pragma unroll
        for (int i = 0; i < NO; ++i) {
            float v = e[i];
#pragma unroll
            for (int k = 0; k < i; ++k) v = fmaf(-M[i][k], wv[k], v);
            wv[i] = v * drs[i];
            quad = fmaf(wv[i], wv[i], quad);
        }
        const float SCALE = 0.5f / ((float)BN * (float)TT * (float)NO);
        contrib = -(logdet + quad) * SCALE;
    }
#pragma unroll
    for (int off = 32; off > 0; off >>= 1) contrib += __shfl_down(contrib, off);
    if ((tid & 63) == 0) ssum[tid >> 6] = contrib;
    __syncthreads();
    if (tid == 0) {
        float s = ssum[0] + ssum[1] + ssum[2] + ssum[3];
        if (blockIdx.x == 0) s += C_HALF_LOG2PI;
        atomicAdd(out, s);
    }
}

// ---------------- launch ---------------------------------------------------
extern "C" void kernel_launch(void* const* d_in, const int* in_sizes, int n_in,
                              void* d_out, int out_size, void* d_ws, size_t ws_size,
                              hipStream_t stream) {
    const float* Yi    = (const float*)d_in[0];
    const float* Xh    = (const float*)d_in[1];
    const float* Cw    = (const float*)d_in[2];
    const float* Hm    = (const float*)d_in[3];
    const float* mu_w  = (const float*)d_in[4];
    const float* Wi    = (const float*)d_in[5];
    const float* Wh    = (const float*)d_in[6];
    const float* bi    = (const float*)d_in[7];
    const float* bh    = (const float*)d_in[8];
    const float* W_mu  = (const float*)d_in[9];
    const float* b_mu  = (const float*)d_in[10];
    const float* W_var = (const float*)d_in[11];
    const float* b_var = (const float*)d_in[12];
    float* out = (float*)d_out;

    hipMemsetAsync(d_out, 0, sizeof(float), stream);   // lik adds the constant

    const size_t need_h = (size_t)BN * TT * HID * sizeof(__half);  // 32.77 MB
    if (ws_size >= need_h) {
        __half* hbuf = (__half*)d_ws;
        gru_h<<<dim3(BN), dim3(256), 0, stream>>>(Yi, Xh, Wi, Wh, bi, bh, hbuf);
        lik_h<<<dim3((BN * TT + 255) / 256), dim3(256), 0, stream>>>(
            Yi, Cw, Hm, mu_w, W_mu, b_mu, W_var, b_var, hbuf, out);
    } else {
        float* mv = (float*)d_ws;   // [BN*TT*DIN] floats = 20.48 MB
        gru_fb<<<dim3(BN), dim3(256), 0, stream>>>(Yi, Xh, Wi, Wh, bi, bh,
                                                   W_mu, W_var, mv);
        lik_fb<<<dim3((BN * TT + 255) / 256), dim3(256), 0, stream>>>(
            Yi, Cw, Hm, mu_w, b_mu, b_var, mv, out);
    }
}